// Round 3
// baseline (181.232 us; speedup 1.0000x reference)
//
#include <hip/hip_runtime.h>
#include <stdint.h>

#define H_ 192
#define W_ 192
#define C_ 64
#define EPS_F 1e-8f
#define TILE 16
#define CHUNK 64
#define NSLICE 32

typedef unsigned long long ull;

// Output layout (floats), concatenated in reference return order:
// feats (H*W*C) | p2f (H*W) | zbuf (H*W) | bary (H*W*3) | dists (H*W)
#define OFF_FEATS 0
#define OFF_P2F   (H_*W_*C_)
#define OFF_ZBUF  (OFF_P2F + H_*W_)
#define OFF_BARY  (OFF_ZBUF + H_*W_)
#define OFF_DIST  (OFF_BARY + H_*W_*3)

// IEEE-exact ops (block FMA contraction; match numpy float32 op-for-op)
__device__ __forceinline__ float xm(float a, float b){ return __fmul_rn(a,b); }
__device__ __forceinline__ float xa(float a, float b){ return __fadd_rn(a,b); }
__device__ __forceinline__ float xsb(float a, float b){ return __fsub_rn(a,b); }
__device__ __forceinline__ float xd(float a, float b){ return __fdiv_rn(a,b); }

__device__ __forceinline__ float pixcoord(int i, float dim){
    float t = xa(xm(2.0f, (float)i), 1.0f);
    return xsb(1.0f, xd(t, dim));
}

// Fused: key-buffer init + live-face counter zero + vertex transform
__global__ void k_init(const float* __restrict__ pos, const float* __restrict__ K,
                       const float* __restrict__ RT, float* __restrict__ verts,
                       ull* __restrict__ keys, int* __restrict__ cnt, int V){
    int i = blockIdx.x*blockDim.x + threadIdx.x;
    if (i == 0) *cnt = 0;
    if (i < H_*W_) keys[i] = 0xFFFFFFFFFFFFFFFFULL;
    if (i >= V) return;
    float p0 = pos[3*i+0], p1 = pos[3*i+1], p2 = pos[3*i+2];
    const float sgn[3] = {-1.f, -1.f, 1.f};
    float vv[3];
    #pragma unroll
    for (int j=0;j<3;j++){
        float rp0 = xm(RT[j*4+0], sgn[j]);
        float rp1 = xm(RT[j*4+1], sgn[j]);
        float rp2 = xm(RT[j*4+2], sgn[j]);
        float s = xa(xa(xm(p0,rp0), xm(p1,rp1)), xm(p2,rp2));
        vv[j] = xa(s, xm(RT[j*4+3], sgn[j]));
    }
    float z = vv[2];
    const float scale = 96.0f;
    float fx = xd(K[0], scale);
    float fy = xd(K[4], scale);
    float p0x = -xd(xsb(K[2], 96.0f), scale);
    float p0y = -xd(xsb(K[5], 96.0f), scale);
    float xn = xa(xd(xm(fx, vv[0]), z), p0x);
    float yn = xa(xd(xm(fy, vv[1]), z), p0y);
    verts[4*i+0] = xn; verts[4*i+1] = yn; verts[4*i+2] = z; verts[4*i+3] = 0.f;
}

// Compacted live-face records (16 floats each):
// q0: x0,y0,x1,y1 | q1: x2,y2,z0,z1 | q2: z2,ia,zmin,fidx(bits) | q3: xmin,xmax,ymin,ymax
__global__ void k_faces(const int* __restrict__ faces, const float* __restrict__ verts,
                        float* __restrict__ rec, int* __restrict__ cnt, int Fn){
    int f = blockIdx.x*blockDim.x + threadIdx.x;
    int lane = threadIdx.x & 63;
    bool ok = false;
    float x0=0,y0=0,z0=0,x1=0,y1=0,z1=0,x2=0,y2=0,z2=0,inv_area=0;
    if (f < Fn){
        int i0 = faces[3*f+0], i1 = faces[3*f+1], i2 = faces[3*f+2];
        x0=verts[4*i0+0]; y0=verts[4*i0+1]; z0=verts[4*i0+2];
        x1=verts[4*i1+0]; y1=verts[4*i1+1]; z1=verts[4*i1+2];
        x2=verts[4*i2+0]; y2=verts[4*i2+1]; z2=verts[4*i2+2];
        float area = xsb(xm(xsb(x1,x0), xsb(y2,y0)), xm(xsb(y1,y0), xsb(x2,x0)));
        ok = (area > EPS_F) && (z0 > 0.f) && (z1 > 0.f) && (z2 > 0.f);
        if (ok) inv_area = xd(1.0f, area);
    }
    ull m = __ballot(ok);
    int nw = __popcll(m);
    if (nw == 0) return;
    int leader = __ffsll((long long)m) - 1;
    int base = 0;
    if (lane == leader) base = atomicAdd(cnt, nw);
    base = __shfl(base, leader);
    if (!ok) return;
    int pos = base + __popcll(m & ((1ULL << lane) - 1ULL));
    float xmn = fminf(x0, fminf(x1, x2)) - 1e-4f;
    float xmx = fmaxf(x0, fmaxf(x1, x2)) + 1e-4f;
    float ymn = fminf(y0, fminf(y1, y2)) - 1e-4f;
    float ymx = fmaxf(y0, fmaxf(y1, y2)) + 1e-4f;
    float zmn = fminf(z0, fminf(z1, z2));
    float4* q = (float4*)(rec + (size_t)pos*16);
    q[0] = make_float4(x0, y0, x1, y1);
    q[1] = make_float4(x2, y2, z0, z1);
    q[2] = make_float4(z2, inv_area, zmn, __int_as_float(f));
    q[3] = make_float4(xmn, xmx, ymn, ymx);
}

__global__ __launch_bounds__(64) void k_raster(const float* __restrict__ rec,
        const int* __restrict__ cnt, ull* __restrict__ keys){
    __shared__ float lf[CHUNK*12];
    __shared__ float zl[CHUNK];
    __shared__ int   fi[CHUNK];
    int lane = threadIdx.x;
    int ix  = blockIdx.x*TILE + (lane & 15);
    int iy0 = blockIdx.y*TILE + (lane >> 4) * 4;   // thread owns rows iy0..iy0+3
    float px = pixcoord(ix, (float)W_);
    float py[4]; int pix[4];
    #pragma unroll
    for (int r=0;r<4;r++){ py[r] = pixcoord(iy0+r, (float)H_); pix[r] = (iy0+r)*W_ + ix; }
    float tx_hi = pixcoord(blockIdx.x*TILE,          (float)W_);
    float tx_lo = pixcoord(blockIdx.x*TILE + TILE-1, (float)W_);
    float ty_hi = pixcoord(blockIdx.y*TILE,          (float)H_);
    float ty_lo = pixcoord(blockIdx.y*TILE + TILE-1, (float)H_);
    int alive = *cnt;
    int perSlice = (alive + NSLICE - 1) / NSLICE;
    int f0 = blockIdx.z * perSlice;
    int f1 = min(f0 + perSlice, alive);

    float zbest[4], zskip[4]; int fbest[4], lastf[4];
    #pragma unroll
    for (int r=0;r<4;r++){ zbest[r]=INFINITY; zskip[r]=INFINITY; fbest[r]=-1; lastf[r]=-1; }

    for (int base = f0; base < f1; base += CHUNK){
        // refresh conservative skip-depth from global keys (device-scope load)
        float zmax;
        {
            #pragma unroll
            for (int r=0;r<4;r++){
                ull k = __hip_atomic_load(&keys[pix[r]], __ATOMIC_RELAXED, __HIP_MEMORY_SCOPE_AGENT);
                float kz = __uint_as_float((unsigned)(k >> 32));
                zskip[r] = fminf(zskip[r], kz);
            }
            zmax = fmaxf(fmaxf(zskip[0],zskip[1]), fmaxf(zskip[2],zskip[3]));
        }
        __syncthreads();
        int f = base + lane;
        bool keep = false;
        float4 q0, q1, q2;
        if (f < f1){
            const float4* g = (const float4*)(rec + (size_t)f*16);
            q0 = g[0]; q1 = g[1]; q2 = g[2];
            float4 q3 = g[3];
            keep = (q3.x <= tx_hi) && (q3.y >= tx_lo) && (q3.z <= ty_hi) && (q3.w >= ty_lo);
        }
        ull m = __ballot(keep);
        int nsurv = __popcll(m);
        if (keep){
            int pos = __popcll(m & ((1ULL << lane) - 1ULL));
            float4* l = (float4*)(lf + pos*12);
            l[0] = q0; l[1] = q1; l[2] = q2;
            zl[pos] = q2.z;
            fi[pos] = __float_as_int(q2.w);
        }
        __syncthreads();

        for (int k = 0; k < nsurv; k++){
            float t = xm(zl[k], 0.999f);   // conservative: zp >= zmin*(1-eps)
            if (t >= zmax) continue;
            const float* rr = lf + k*12;
            float x0=rr[0], y0=rr[1], x1=rr[2], y1=rr[3], x2=rr[4], y2=rr[5];
            float dx0=xsb(x0,px), dx1=xsb(x1,px), dx2=xsb(x2,px);
            #pragma unroll
            for (int r=0;r<4;r++){
                float dy0=xsb(y0,py[r]), dy1=xsb(y1,py[r]), dy2=xsb(y2,py[r]);
                float e0 = xsb(xm(dx1,dy2), xm(dy1,dx2));
                float e1 = xsb(xm(dx2,dy0), xm(dy2,dx0));
                float e2 = xsb(xm(dx0,dy1), xm(dy0,dx1));
                if (e0 >= 0.f && e1 >= 0.f && e2 >= 0.f && t < zskip[r]){
                    float z0=rr[6], z1=rr[7], z2=rr[8], ia=rr[9];
                    float w0 = xm(e0, ia), w1 = xm(e1, ia), w2 = xm(e2, ia);
                    float l0 = xm(xm(w0,z1),z2);
                    float l1 = xm(xm(z0,w1),z2);
                    float l2 = xm(xm(z0,z1),w2);
                    float s  = xa(xa(l0,l1),l2);
                    float dn = (s == 0.f) ? 1.0f : s;
                    float b0 = fmaxf(xd(l0,dn), 0.f);
                    float b1 = fmaxf(xd(l1,dn), 0.f);
                    float b2 = fmaxf(xd(l2,dn), 0.f);
                    float bs = fmaxf(xa(xa(b0,b1),b2), EPS_F);
                    b0 = xd(b0,bs); b1 = xd(b1,bs); b2 = xd(b2,bs);
                    float zp = xa(xa(xm(b0,z0),xm(b1,z1)),xm(b2,z2));
                    int fidx = fi[k];
                    if (zp < zbest[r] || (zp == zbest[r] && fidx < fbest[r])){
                        zbest[r] = zp; fbest[r] = fidx;
                        zskip[r] = fminf(zskip[r], zp);
                        zmax = fmaxf(fmaxf(zskip[0],zskip[1]), fmaxf(zskip[2],zskip[3]));
                    }
                }
            }
        }
        // publish improvements so other slices can skip
        #pragma unroll
        for (int r=0;r<4;r++){
            if (fbest[r] >= 0 && fbest[r] != lastf[r]){
                ull key = (((ull)__float_as_uint(zbest[r])) << 32) | (unsigned)fbest[r];
                atomicMin(&keys[pix[r]], key);
                lastf[r] = fbest[r];
            }
        }
    }
}

// Fused resolve + shade: 64 lanes per pixel (lane = channel), 4 pixels/block.
// Recomputes geometry bit-exactly from verts/faces (rec is compacted/permuted).
__global__ __launch_bounds__(256) void k_post(const ull* __restrict__ keys,
        const float* __restrict__ verts, const float* __restrict__ feats,
        const int* __restrict__ faces, float* __restrict__ out){
    int grp = threadIdx.x >> 6;
    int c = threadIdx.x & 63;
    int pix = blockIdx.x*4 + grp;
    float* p2f  = out + OFF_P2F;
    float* zbuf = out + OFF_ZBUF;
    float* bary = out + OFF_BARY;
    float* dist = out + OFF_DIST;
    ull key = keys[pix];
    if (key == 0xFFFFFFFFFFFFFFFFULL){
        out[OFF_FEATS + pix*C_ + c] = 0.0f;
        if (c == 0){ p2f[pix] = -1.0f; zbuf[pix] = -1.0f; dist[pix] = -1.0f; }
        if (c < 3) bary[3*pix+c] = -1.0f;
        return;
    }
    int f = (int)(key & 0xFFFFFFFFu);
    float z = __uint_as_float((unsigned)(key >> 32));
    int ix = pix % W_, iy = pix / W_;
    float px = pixcoord(ix, (float)W_);
    float py = pixcoord(iy, (float)H_);
    int i0 = faces[3*f+0], i1 = faces[3*f+1], i2 = faces[3*f+2];
    float x0=verts[4*i0+0], y0=verts[4*i0+1], z0=verts[4*i0+2];
    float x1=verts[4*i1+0], y1=verts[4*i1+1], z1=verts[4*i1+2];
    float x2=verts[4*i2+0], y2=verts[4*i2+1], z2=verts[4*i2+2];
    float area = xsb(xm(xsb(x1,x0), xsb(y2,y0)), xm(xsb(y1,y0), xsb(x2,x0)));
    float ia = xd(1.0f, area);   // winner is guaranteed a live face
    float w0 = xm(xsb(xm(xsb(x1,px),xsb(y2,py)), xm(xsb(y1,py),xsb(x2,px))), ia);
    float w1 = xm(xsb(xm(xsb(x2,px),xsb(y0,py)), xm(xsb(y2,py),xsb(x0,px))), ia);
    float w2 = xm(xsb(xm(xsb(x0,px),xsb(y1,py)), xm(xsb(y0,py),xsb(x1,px))), ia);
    float l0 = xm(xm(w0,z1),z2);
    float l1 = xm(xm(z0,w1),z2);
    float l2 = xm(xm(z0,z1),w2);
    float s  = xa(xa(l0,l1),l2);
    float dn = (s == 0.f) ? 1.0f : s;
    float b0 = fmaxf(xd(l0,dn), 0.f);
    float b1 = fmaxf(xd(l1,dn), 0.f);
    float b2 = fmaxf(xd(l2,dn), 0.f);
    float bs = fmaxf(xa(xa(b0,b1),b2), EPS_F);
    b0 = xd(b0,bs); b1 = xd(b1,bs); b2 = xd(b2,bs);
    float res = xa(xa(xm(b0, feats[i0*C_ + c]), xm(b1, feats[i1*C_ + c])),
                   xm(b2, feats[i2*C_ + c]));
    out[OFF_FEATS + pix*C_ + c] = res;
    if (c == 0){ p2f[pix] = (float)f; zbuf[pix] = z; dist[pix] = 0.0f; }
    if (c < 3){
        float bb = (c == 0) ? b0 : ((c == 1) ? b1 : b2);
        bary[3*pix+c] = bb;
    }
}

extern "C" void kernel_launch(void* const* d_in, const int* in_sizes, int n_in,
                              void* d_out, int out_size, void* d_ws, size_t ws_size,
                              hipStream_t stream) {
    const float* positions = (const float*)d_in[0];
    const float* features  = (const float*)d_in[1];
    const int*   faces     = (const int*)  d_in[2];
    const float* K         = (const float*)d_in[3];
    const float* RT        = (const float*)d_in[4];
    int V  = in_sizes[0] / 3;   // 8192
    int Fn = in_sizes[2] / 3;   // 16384

    float* verts = (float*)d_ws;                     // V*4 floats
    float* rec   = verts + (size_t)V*4;              // up to Fn*16 floats
    ull*   keys  = (ull*)(rec + (size_t)Fn*16);      // H*W keys
    int*   cnt   = (int*)(keys + (size_t)H_*W_);     // live-face counter

    int initN = H_*W_;  // covers keys (36864) and verts (8192)
    k_init<<<(initN+255)/256, 256, 0, stream>>>(positions, K, RT, verts, keys, cnt, V);
    k_faces<<<(Fn+255)/256, 256, 0, stream>>>(faces, verts, rec, cnt, Fn);
    dim3 rg(W_/TILE, H_/TILE, NSLICE);
    k_raster<<<rg, dim3(64,1,1), 0, stream>>>(rec, cnt, keys);
    k_post<<<(H_*W_)/4, 256, 0, stream>>>(keys, verts, features, faces, (float*)d_out);
}